// Round 5
// baseline (472.539 us; speedup 1.0000x reference)
//
#include <hip/hip_runtime.h>
#include <hip/hip_bf16.h>

// SelfAttention2D: B=4, C=256, H=W=64, N=4096, Cqk=32.
// Round 5: occupancy push. Same register-P flash algorithm as R4 (verified),
// but attn at 1024 threads = 16 waves = 4 waves/SIMD (4 kh-quarters x 4
// cs-slices, LDS tree-combine), and proj split into 5 oc-groups (grid 1280,
// 5 blocks/CU) to fix its 1-wave/SIMD latency exposure.

typedef __attribute__((ext_vector_type(8))) short s8v;  // 8 bf16 (MFMA A/B frag)
typedef __attribute__((ext_vector_type(4))) float f4v;  // MFMA C/D frag

#define NPIX 4096
#define CIN 256
#define DQK 32

#if __has_builtin(__builtin_amdgcn_exp2f)
#define EXP2(x) __builtin_amdgcn_exp2f(x)
#else
#define EXP2(x) exp2f(x)
#endif

static __device__ __forceinline__ unsigned short f2bf(float f) {
    union { float f; unsigned int u; } v; v.f = f;
    unsigned int r = v.u + 0x7FFF + ((v.u >> 16) & 1);   // RTNE
    return (unsigned short)(r >> 16);
}
static __device__ __forceinline__ unsigned int fbits(float f) {
    union { float f; unsigned int u; } v; v.f = f; return v.u;
}

// ---------------------------------------------------------------------------
// Kernel 1: pack Wq/Wk/Wv -> bf16 Wall[320][256], biases -> fp32 ball[320].
__global__ void wcast_kernel(const float* __restrict__ Wq, const float* __restrict__ bq,
                             const float* __restrict__ Wk, const float* __restrict__ bk,
                             const float* __restrict__ Wv, const float* __restrict__ bv,
                             unsigned short* __restrict__ Wall, float* __restrict__ ball) {
    int row = blockIdx.x;
    int t = threadIdx.x;
    const float* src; const float* bsrc;
    if (row < 32)       { src = Wq + row * 256;        bsrc = bq + row; }
    else if (row < 64)  { src = Wk + (row - 32) * 256; bsrc = bk + (row - 32); }
    else                { src = Wv + (row - 64) * 256; bsrc = bv + (row - 64); }
    Wall[row * 256 + t] = f2bf(src[t]);
    if (t == 0) ball[row] = bsrc[0];
}

// ---------------------------------------------------------------------------
// Kernel 2: x[b][c][n] fp32 -> xT[b][n][c] bf16 (64x64 LDS tile transpose).
__global__ void tcast_kernel(const float* __restrict__ x, unsigned short* __restrict__ xT) {
    __shared__ unsigned short tile[64][65];
    int bidx = blockIdx.x;
    int b    = bidx >> 8;
    int cblk = (bidx >> 6) & 3;
    int nblk = bidx & 63;
    int t = threadIdx.x;
    int c0 = cblk * 64, n0 = nblk * 64;
    const float* xb = x + (size_t)b * CIN * NPIX;
    #pragma unroll
    for (int p = 0; p < 4; p++) {
        int cl = p * 16 + (t >> 4);
        int nl = (t & 15) * 4;
        float4 v = *(const float4*)(xb + (size_t)(c0 + cl) * NPIX + n0 + nl);
        tile[cl][nl + 0] = f2bf(v.x);
        tile[cl][nl + 1] = f2bf(v.y);
        tile[cl][nl + 2] = f2bf(v.z);
        tile[cl][nl + 3] = f2bf(v.w);
    }
    __syncthreads();
    unsigned short* xTb = xT + (size_t)b * NPIX * CIN;
    #pragma unroll
    for (int p = 0; p < 4; p++) {
        int nl = p * 16 + (t >> 4);
        int cl = (t & 15) * 4;
        ushort4 wv;
        wv.x = tile[cl + 0][nl];
        wv.y = tile[cl + 1][nl];
        wv.z = tile[cl + 2][nl];
        wv.w = tile[cl + 3][nl];
        *(ushort4*)(xTb + (size_t)(n0 + nl) * CIN + c0 + cl) = wv;
    }
}

// ---------------------------------------------------------------------------
// Kernel 3: projection GEMM, grid = 5 oc-groups x 256 (b,nblk) = 1280 blocks
// (5 blocks/CU). Group 0 = Q pair + K~ pair; groups 1..4 = V pairs.
__global__ __launch_bounds__(256)
void proj_kernel(const unsigned short* __restrict__ xT,
                 const unsigned short* __restrict__ Wall,
                 const float* __restrict__ ball,
                 unsigned short* __restrict__ Q,
                 unsigned short* __restrict__ Kp,
                 unsigned short* __restrict__ Vt) {
    int g    = blockIdx.x;
    int oq   = g >> 8;                               // 0..4
    int idx  = g & 255;
    int b    = (idx & 7) >> 1;                       // XCD affinity (matches attn)
    int nblk = ((idx >> 3) << 1) | (idx & 1);
    int w    = threadIdx.x >> 6;
    int lane = threadIdx.x & 63;
    int l16 = lane & 15, quad = lane >> 4;
    int n0 = nblk * 64 + w * 16;

    const unsigned short* brow = xT + (size_t)(b * NPIX + n0 + l16) * CIN + quad * 8;
    s8v bfr[8];
    #pragma unroll
    for (int kk = 0; kk < 8; kk++) bfr[kk] = *(const s8v*)(brow + kk * 32);

    #pragma unroll
    for (int pp = 0; pp < 2; pp++) {
        int ob0 = oq * 4 + 2 * pp;
        const unsigned short* w0 = Wall + (size_t)(ob0 * 16 + l16) * CIN + quad * 8;
        const unsigned short* w1 = w0 + 16 * CIN;
        f4v a0 = {0.f, 0.f, 0.f, 0.f}, a1 = {0.f, 0.f, 0.f, 0.f};
        if (ob0 < 4) {  // Q/K pairs: A=xT(rows=n), B=W(cols=oc)
            #pragma unroll
            for (int kk = 0; kk < 8; kk++) {
                a0 = __builtin_amdgcn_mfma_f32_16x16x32_bf16(bfr[kk], *(const s8v*)(w0 + kk * 32), a0, 0, 0, 0);
                a1 = __builtin_amdgcn_mfma_f32_16x16x32_bf16(bfr[kk], *(const s8v*)(w1 + kk * 32), a1, 0, 0, 0);
            }
        } else {        // V pairs: A=W(rows=ch), B=xT(cols=n)
            #pragma unroll
            for (int kk = 0; kk < 8; kk++) {
                a0 = __builtin_amdgcn_mfma_f32_16x16x32_bf16(*(const s8v*)(w0 + kk * 32), bfr[kk], a0, 0, 0, 0);
                a1 = __builtin_amdgcn_mfma_f32_16x16x32_bf16(*(const s8v*)(w1 + kk * 32), bfr[kk], a1, 0, 0, 0);
            }
        }
        #pragma unroll
        for (int half = 0; half < 2; half++) {
            int ob = ob0 + half;
            f4v acc = half ? a1 : a0;
            if (ob < 2) {            // Q: lane l16 = oc, reg r -> n-sub
                int oc = ob * 16 + l16;
                float bias = ball[oc];
                #pragma unroll
                for (int r = 0; r < 4; r++) {
                    int n = n0 + quad * 4 + r;
                    Q[(size_t)(b * NPIX + n) * DQK + oc] =
                        f2bf((acc[r] + bias) * 1.44269504f);
                }
            } else if (ob < 4) {     // K~: permuted row sigma^-1(n)
                int oc = (ob - 2) * 16 + l16;
                float bias = ball[32 + oc];
                #pragma unroll
                for (int r = 0; r < 4; r++) {
                    int n = n0 + quad * 4 + r;
                    int pn = (n & ~31) | (((n >> 2) & 1) << 4) | (((n >> 3) & 3) << 2) | (n & 3);
                    Kp[(size_t)(b * NPIX + pn) * DQK + oc] = f2bf(acc[r] + bias);
                }
            } else {                 // V: lane l16 = n, reg r -> ch-sub
                int n = n0 + l16;
                #pragma unroll
                for (int r = 0; r < 4; r++) {
                    int ch = (ob - 4) * 16 + quad * 4 + r;
                    Vt[((size_t)b * CIN + ch) * NPIX + n] = f2bf(acc[r] + ball[64 + ch]);
                }
            }
        }
    }
}

// ---------------------------------------------------------------------------
// Kernel 4: flash attention. 1024 threads = 16 waves: w = kh*4 + cs.
// Wave (kh,cs): keys {32kh + 128j, j=0..31} (32/step), all 64 q-rows,
// ch slice [cs*64, +64). End: lsum partials via ldsL; O partials combined in
// 3 sequential LDS rounds (kh=j writes, kh=0 accumulates); kh=0 stores.
#define ATTN_STEP(KC0, KC1, VC, KN0, KN1, VN, NKV)                              \
    {                                                                           \
        KN0 = *(const s8v*)(kbase + (NKV) * DQK);                               \
        KN1 = *(const s8v*)(kbase + ((NKV) + 16) * DQK);                        \
        _Pragma("unroll")                                                       \
        for (int ct = 0; ct < 4; ct++)                                          \
            VN[ct] = *(const s8v*)(vbase + ct * 16 * NPIX + (NKV));             \
        s8v pu[4];                                                              \
        _Pragma("unroll")                                                       \
        for (int rt = 0; rt < 4; rt++) {                                        \
            f4v s0 = {0.f, 0.f, 0.f, 0.f}, s1 = {0.f, 0.f, 0.f, 0.f};           \
            s0 = __builtin_amdgcn_mfma_f32_16x16x32_bf16(KC0, qf[rt], s0, 0, 0, 0); \
            s1 = __builtin_amdgcn_mfma_f32_16x16x32_bf16(KC1, qf[rt], s1, 0, 0, 0); \
            float p00 = EXP2(s0[0]), p01 = EXP2(s0[1]);                         \
            float p02 = EXP2(s0[2]), p03 = EXP2(s0[3]);                         \
            float p10 = EXP2(s1[0]), p11 = EXP2(s1[1]);                         \
            float p12 = EXP2(s1[2]), p13 = EXP2(s1[3]);                         \
            lsum[rt] += ((p00 + p01) + (p02 + p03)) + ((p10 + p11) + (p12 + p13)); \
            union { uint4 u; s8v v; } pp;                                       \
            pp.u.x = __builtin_amdgcn_perm(fbits(p01), fbits(p00), 0x07060302); \
            pp.u.y = __builtin_amdgcn_perm(fbits(p03), fbits(p02), 0x07060302); \
            pp.u.z = __builtin_amdgcn_perm(fbits(p11), fbits(p10), 0x07060302); \
            pp.u.w = __builtin_amdgcn_perm(fbits(p13), fbits(p12), 0x07060302); \
            pu[rt] = pp.v;                                                      \
        }                                                                       \
        _Pragma("unroll")                                                       \
        for (int ct = 0; ct < 4; ct++)                                          \
            _Pragma("unroll")                                                   \
            for (int rt = 0; rt < 4; rt++)                                      \
                O[rt][ct] = __builtin_amdgcn_mfma_f32_16x16x32_bf16(VC[ct], pu[rt], O[rt][ct], 0, 0, 0); \
    }

__global__ __launch_bounds__(1024, 4)
void attn_kernel(const unsigned short* __restrict__ Q,
                 const unsigned short* __restrict__ Kp,
                 const unsigned short* __restrict__ Vt,
                 const float* __restrict__ gamma,
                 float* __restrict__ out) {
    __shared__ float ldsO[4][64][68];   // one kh-partial: [cs][lane][16 f4v +pad]
    __shared__ float ldsL[3][4][16];    // kh=1..3 row-sums per (rt, l16)

    int idx = blockIdx.x;
    int b      = (idx & 7) >> 1;                    // batch -> XCD pair
    int rowblk = ((idx >> 3) << 1) | (idx & 1);

    int lane = threadIdx.x & 63;
    int w    = threadIdx.x >> 6;                    // 0..15
    int l16 = lane & 15, quad = lane >> 4;
    int kh = w >> 2;     // key quarter 0..3
    int cs = w & 3;      // 64-ch slice 0..3

    const unsigned short* Kb = Kp + (size_t)b * NPIX * DQK;
    const unsigned short* Vb = Vt + (size_t)b * CIN * NPIX;

    int rowbase = rowblk * 64;
    s8v qf[4];
    #pragma unroll
    for (int rt = 0; rt < 4; rt++)
        qf[rt] = *(const s8v*)(Q + (size_t)(b * NPIX + rowbase + rt * 16 + l16) * DQK + quad * 8);

    const unsigned short* kbase = Kb + (32 * kh + l16) * DQK + quad * 8;
    const unsigned short* vbase = Vb + (size_t)(cs * 64 + l16) * NPIX + 32 * kh + quad * 8;

    f4v O[4][4];
    #pragma unroll
    for (int rt = 0; rt < 4; rt++)
        #pragma unroll
        for (int ct = 0; ct < 4; ct++) O[rt][ct] = (f4v){0.f, 0.f, 0.f, 0.f};
    float lsum[4] = {0.f, 0.f, 0.f, 0.f};

    s8v Vc[4], Vn[4], Kc0, Kc1, Kn0, Kn1;
    Kc0 = *(const s8v*)(kbase);
    Kc1 = *(const s8v*)(kbase + 16 * DQK);
    #pragma unroll
    for (int ct = 0; ct < 4; ct++)
        Vc[ct] = *(const s8v*)(vbase + ct * 16 * NPIX);

    for (int kv2 = 0; kv2 < NPIX; kv2 += 256) {
        ATTN_STEP(Kc0, Kc1, Vc, Kn0, Kn1, Vn, kv2 + 128);
        ATTN_STEP(Kn0, Kn1, Vn, Kc0, Kc1, Vc, (kv2 + 256) & (NPIX - 1));
    }

    // row-sums for this key quarter (reduce over quads; all lanes get value)
    #pragma unroll
    for (int rt = 0; rt < 4; rt++) {
        lsum[rt] += __shfl_xor(lsum[rt], 16);
        lsum[rt] += __shfl_xor(lsum[rt], 32);
    }
    if (kh > 0 && cs == 0 && quad == 0) {
        #pragma unroll
        for (int rt = 0; rt < 4; rt++) ldsL[kh - 1][rt][l16] = lsum[rt];
    }

    // 3 sequential combine rounds: kh=j publishes, kh=0 accumulates
    for (int j = 1; j <= 3; j++) {
        if (kh == j) {
            #pragma unroll
            for (int rt = 0; rt < 4; rt++)
                #pragma unroll
                for (int ct = 0; ct < 4; ct++)
                    *(f4v*)&ldsO[cs][lane][(rt * 4 + ct) * 4] = O[rt][ct];
        }
        __syncthreads();
        if (kh == 0) {
            #pragma unroll
            for (int rt = 0; rt < 4; rt++)
                #pragma unroll
                for (int ct = 0; ct < 4; ct++)
                    O[rt][ct] += *(const f4v*)&ldsO[cs][lane][(rt * 4 + ct) * 4];
        }
        __syncthreads();
    }

    if (kh == 0) {
        float g = gamma[0];
        float rinv[4];
        #pragma unroll
        for (int rt = 0; rt < 4; rt++)
            rinv[rt] = g / (lsum[rt] + ldsL[0][rt][l16] + ldsL[1][rt][l16] + ldsL[2][rt][l16]);
        #pragma unroll
        for (int rt = 0; rt < 4; rt++) {
            #pragma unroll
            for (int ct = 0; ct < 4; ct++) {
                #pragma unroll
                for (int r = 0; r < 4; r++) {
                    int ch = cs * 64 + ct * 16 + quad * 4 + r;
                    out[((size_t)b * CIN + ch) * NPIX + rowbase + rt * 16 + l16] =
                        O[rt][ct][r] * rinv[rt];
                }
            }
        }
    }
}

// ---------------------------------------------------------------------------
extern "C" void kernel_launch(void* const* d_in, const int* in_sizes, int n_in,
                              void* d_out, int out_size, void* d_ws, size_t ws_size,
                              hipStream_t stream) {
    const float* x     = (const float*)d_in[0];
    const float* Wq    = (const float*)d_in[1];
    const float* bq    = (const float*)d_in[2];
    const float* Wk    = (const float*)d_in[3];
    const float* bk    = (const float*)d_in[4];
    const float* Wv    = (const float*)d_in[5];
    const float* bv    = (const float*)d_in[6];
    const float* gamma = (const float*)d_in[7];
    float* out = (float*)d_out;

    char* p = (char*)d_ws;
    unsigned short* xT   = (unsigned short*)p; p += (size_t)4 * NPIX * CIN * 2;   // 8 MB
    unsigned short* Qb   = (unsigned short*)p; p += (size_t)4 * NPIX * DQK * 2;   // 1 MB
    unsigned short* Kb   = (unsigned short*)p; p += (size_t)4 * NPIX * DQK * 2;   // 1 MB
    unsigned short* Vt   = (unsigned short*)p; p += (size_t)4 * CIN * NPIX * 2;   // 8 MB
    unsigned short* Wall = (unsigned short*)p; p += (size_t)320 * 256 * 2;
    float*          ball = (float*)p;          p += (size_t)320 * 4;

    wcast_kernel<<<320, 256, 0, stream>>>(Wq, bq, Wk, bk, Wv, bv, Wall, ball);
    tcast_kernel<<<1024, 256, 0, stream>>>(x, xT);
    proj_kernel<<<1280, 256, 0, stream>>>(xT, Wall, ball, Qb, Kb, Vt);
    attn_kernel<<<256, 1024, 0, stream>>>(Qb, Kb, Vt, gamma, out);
}

// Round 6
// 266.912 us; speedup vs baseline: 1.7704x; 1.7704x over previous
//
#include <hip/hip_runtime.h>
#include <hip/hip_bf16.h>

// SelfAttention2D: B=4, C=256, H=W=64, N=4096, Cqk=32.
// Round 6:
//  - prep_kernel fuses wcast+tcast+proj: per-block LDS transpose of its own
//    x slice (frag-major), on-the-fly W fp32->bf16 frags, direct Q/K~/V
//    stores. Removes 2 dispatches + 8MB xT round-trip.
//  - attn: R4 dataflow at 32 rows/block, grid 512, JIT V loads (no Vn
//    prefetch) -> ~110 unified regs -> TRUE 2 blocks/CU (4 waves/SIMD).
//    R5 lesson: unified VGPR+AGPR budget; never cap below true need.

typedef __attribute__((ext_vector_type(8))) short s8v;  // 8 bf16 (MFMA A/B frag)
typedef __attribute__((ext_vector_type(4))) float f4v;  // MFMA C/D frag

#define NPIX 4096
#define CIN 256
#define DQK 32

#if __has_builtin(__builtin_amdgcn_exp2f)
#define EXP2(x) __builtin_amdgcn_exp2f(x)
#else
#define EXP2(x) exp2f(x)
#endif

static __device__ __forceinline__ unsigned short f2bf(float f) {
    union { float f; unsigned int u; } v; v.f = f;
    unsigned int r = v.u + 0x7FFF + ((v.u >> 16) & 1);   // RTNE
    return (unsigned short)(r >> 16);
}
static __device__ __forceinline__ unsigned int fbits(float f) {
    union { float f; unsigned int u; } v; v.f = f; return v.u;
}
static __device__ __forceinline__ s8v loadpack_bf16(const float* p) {
    float4 a = *(const float4*)p;
    float4 b = *(const float4*)(p + 4);
    union { unsigned short us[8]; s8v v; } u;
    u.us[0] = f2bf(a.x); u.us[1] = f2bf(a.y); u.us[2] = f2bf(a.z); u.us[3] = f2bf(a.w);
    u.us[4] = f2bf(b.x); u.us[5] = f2bf(b.y); u.us[6] = f2bf(b.z); u.us[7] = f2bf(b.w);
    return u.v;
}

// ---------------------------------------------------------------------------
// Kernel 1: fused prep. grid = 512 blocks (b, 32-row slice), 256 threads.
// Phase 1: transpose-cast x[b][:, n0..n0+32] -> LDS (frag-major bf16).
// Phase 2: 4 waves = (row-tile wr x oc-half wo); W converted on the fly;
// stores Q (x log2e, +bq), K~ (sigma-permuted rows, +bk), Vt (+bv).
__global__ __launch_bounds__(256)
void prep_kernel(const float* __restrict__ x,
                 const float* __restrict__ Wq, const float* __restrict__ bq,
                 const float* __restrict__ Wk, const float* __restrict__ bk,
                 const float* __restrict__ Wv, const float* __restrict__ bv,
                 unsigned short* __restrict__ Q,
                 unsigned short* __restrict__ Kp,
                 unsigned short* __restrict__ Vt) {
    __shared__ unsigned short xLDS[32 * 256];   // frag-major: unit u=(kk*4+quad)*32+n, 8 shorts each

    int idx = blockIdx.x;
    int b   = (idx & 7) >> 1;                    // XCD affinity (matches attn)
    int nb  = ((idx >> 3) << 1) | (idx & 1);     // 0..127
    int n0  = nb * 32;
    int t   = threadIdx.x;

    // Phase 1: coalesced read along n, scatter bf16 into frag-major LDS
    {
        int nloc  = (t & 7) * 4;
        int cbase = t >> 3;                      // 0..31
        const float* xb = x + (size_t)b * CIN * NPIX + n0 + nloc;
        #pragma unroll
        for (int i = 0; i < 8; i++) {
            int c = i * 32 + cbase;
            float4 v = *(const float4*)(xb + (size_t)c * NPIX);
            int kk = c >> 5, quad = (c >> 3) & 3, off = c & 7;
            unsigned short* dst = &xLDS[((kk * 4 + quad) * 32) * 8 + off];
            dst[(nloc + 0) * 8] = f2bf(v.x);
            dst[(nloc + 1) * 8] = f2bf(v.y);
            dst[(nloc + 2) * 8] = f2bf(v.z);
            dst[(nloc + 3) * 8] = f2bf(v.w);
        }
    }
    __syncthreads();

    // Phase 2: GEMM
    int lane = t & 63, w = t >> 6;
    int l16 = lane & 15, quad = lane >> 4;
    int wr = w & 1, wo = w >> 1;
    int nrow0 = 16 * wr;

    s8v bfr[8];
    #pragma unroll
    for (int kk = 0; kk < 8; kk++)
        bfr[kk] = *(const s8v*)&xLDS[(((kk * 4 + quad) * 32) + nrow0 + l16) * 8];

    #pragma unroll
    for (int pp = 0; pp < 5; pp++) {
        int ob0 = wo * 10 + 2 * pp;              // pairs never straddle Q/K/V boundaries
        const float* wsrc; const float* bsrc; int rowbase_w;
        if (ob0 < 2)      { wsrc = Wq; bsrc = bq; rowbase_w = ob0 * 16; }
        else if (ob0 < 4) { wsrc = Wk; bsrc = bk; rowbase_w = (ob0 - 2) * 16; }
        else              { wsrc = Wv; bsrc = bv; rowbase_w = (ob0 - 4) * 16; }
        const float* w0p = wsrc + (size_t)(rowbase_w + l16) * CIN + quad * 8;
        const float* w1p = w0p + 16 * CIN;

        f4v acc0 = {0.f, 0.f, 0.f, 0.f}, acc1 = {0.f, 0.f, 0.f, 0.f};
        if (ob0 < 4) {  // Q/K: A=x(rows=n), B=W(cols=oc)
            #pragma unroll
            for (int kk = 0; kk < 8; kk++) {
                s8v w0f = loadpack_bf16(w0p + kk * 32);
                s8v w1f = loadpack_bf16(w1p + kk * 32);
                acc0 = __builtin_amdgcn_mfma_f32_16x16x32_bf16(bfr[kk], w0f, acc0, 0, 0, 0);
                acc1 = __builtin_amdgcn_mfma_f32_16x16x32_bf16(bfr[kk], w1f, acc1, 0, 0, 0);
            }
        } else {        // V: A=W(rows=ch), B=x(cols=n)
            #pragma unroll
            for (int kk = 0; kk < 8; kk++) {
                s8v w0f = loadpack_bf16(w0p + kk * 32);
                s8v w1f = loadpack_bf16(w1p + kk * 32);
                acc0 = __builtin_amdgcn_mfma_f32_16x16x32_bf16(w0f, bfr[kk], acc0, 0, 0, 0);
                acc1 = __builtin_amdgcn_mfma_f32_16x16x32_bf16(w1f, bfr[kk], acc1, 0, 0, 0);
            }
        }

        #pragma unroll
        for (int half = 0; half < 2; half++) {
            int ob = ob0 + half;
            f4v acc = half ? acc1 : acc0;
            if (ob < 2) {            // Q: col l16 = oc, row quad*4+r = n-sub
                int oc = ob * 16 + l16;
                float bias = bsrc[oc];
                #pragma unroll
                for (int r = 0; r < 4; r++) {
                    int n = n0 + nrow0 + quad * 4 + r;
                    Q[(size_t)(b * NPIX + n) * DQK + oc] =
                        f2bf((acc[r] + bias) * 1.44269504f);
                }
            } else if (ob < 4) {     // K~: sigma-permuted row
                int oc = (ob - 2) * 16 + l16;
                float bias = bsrc[oc];
                #pragma unroll
                for (int r = 0; r < 4; r++) {
                    int n = n0 + nrow0 + quad * 4 + r;
                    int pn = (n & ~31) | (((n >> 2) & 1) << 4) | (((n >> 3) & 3) << 2) | (n & 3);
                    Kp[(size_t)(b * NPIX + pn) * DQK + oc] = f2bf(acc[r] + bias);
                }
            } else {                 // V: col l16 = n, row quad*4+r = ch-sub
                int n = n0 + nrow0 + l16;
                #pragma unroll
                for (int r = 0; r < 4; r++) {
                    int ch = (ob - 4) * 16 + quad * 4 + r;
                    Vt[((size_t)b * CIN + ch) * NPIX + n] = f2bf(acc[r] + bsrc[ch]);
                }
            }
        }
    }
}

// ---------------------------------------------------------------------------
// Kernel 2: flash attention. 32 q-rows/block, grid 512 (2 blocks/CU).
// 8 waves: w = kh*4 + cs. Wave (kh,cs): key set {32kh + 64j}, both row-tiles,
// ch slice [cs*64,+64). K depth-1 prefetch; V JIT (hidden by S/exp + 4w/SIMD).
#define ATTN_STEP(KC0, KC1, KN0, KN1, NKV_NEXT, NKV_CUR)                        \
    {                                                                           \
        KN0 = *(const s8v*)(kbase + (NKV_NEXT) * DQK);                          \
        KN1 = *(const s8v*)(kbase + ((NKV_NEXT) + 16) * DQK);                   \
        s8v Vc[4];                                                              \
        _Pragma("unroll")                                                       \
        for (int ct = 0; ct < 4; ct++)                                          \
            Vc[ct] = *(const s8v*)(vbase + ct * 16 * NPIX + (NKV_CUR));         \
        s8v pu[2];                                                              \
        _Pragma("unroll")                                                       \
        for (int rt = 0; rt < 2; rt++) {                                        \
            f4v s0 = {0.f, 0.f, 0.f, 0.f}, s1 = {0.f, 0.f, 0.f, 0.f};           \
            s0 = __builtin_amdgcn_mfma_f32_16x16x32_bf16(KC0, qf[rt], s0, 0, 0, 0); \
            s1 = __builtin_amdgcn_mfma_f32_16x16x32_bf16(KC1, qf[rt], s1, 0, 0, 0); \
            float p00 = EXP2(s0[0]), p01 = EXP2(s0[1]);                         \
            float p02 = EXP2(s0[2]), p03 = EXP2(s0[3]);                         \
            float p10 = EXP2(s1[0]), p11 = EXP2(s1[1]);                         \
            float p12 = EXP2(s1[2]), p13 = EXP2(s1[3]);                         \
            lsum[rt] += ((p00 + p01) + (p02 + p03)) + ((p10 + p11) + (p12 + p13)); \
            union { uint4 u; s8v v; } pp;                                       \
            pp.u.x = __builtin_amdgcn_perm(fbits(p01), fbits(p00), 0x07060302); \
            pp.u.y = __builtin_amdgcn_perm(fbits(p03), fbits(p02), 0x07060302); \
            pp.u.z = __builtin_amdgcn_perm(fbits(p11), fbits(p10), 0x07060302); \
            pp.u.w = __builtin_amdgcn_perm(fbits(p13), fbits(p12), 0x07060302); \
            pu[rt] = pp.v;                                                      \
        }                                                                       \
        _Pragma("unroll")                                                       \
        for (int ct = 0; ct < 4; ct++)                                          \
            _Pragma("unroll")                                                   \
            for (int rt = 0; rt < 2; rt++)                                      \
                O[rt][ct] = __builtin_amdgcn_mfma_f32_16x16x32_bf16(Vc[ct], pu[rt], O[rt][ct], 0, 0, 0); \
    }

__global__ __launch_bounds__(512, 4)
void attn_kernel(const unsigned short* __restrict__ Q,
                 const unsigned short* __restrict__ Kp,
                 const unsigned short* __restrict__ Vt,
                 const float* __restrict__ gamma,
                 float* __restrict__ out) {
    __shared__ float ldsO[4][64][34];   // kh=1 partial: [cs][lane][8 f4v + pad]
    __shared__ float ldsL[2][16];       // kh=1 row-sums per (rt, l16)

    int idx = blockIdx.x;
    int b      = (idx & 7) >> 1;                    // batch -> XCD pair
    int rowblk = ((idx >> 3) << 1) | (idx & 1);     // 0..127

    int lane = threadIdx.x & 63;
    int w    = threadIdx.x >> 6;
    int l16 = lane & 15, quad = lane >> 4;
    int kh = w >> 2;     // key-half 0..1
    int cs = w & 3;      // 64-ch slice 0..3

    const unsigned short* Kb = Kp + (size_t)b * NPIX * DQK;
    const unsigned short* Vb = Vt + (size_t)b * CIN * NPIX;

    int rowbase = rowblk * 32;
    s8v qf[2];
    #pragma unroll
    for (int rt = 0; rt < 2; rt++)
        qf[rt] = *(const s8v*)(Q + (size_t)(b * NPIX + rowbase + rt * 16 + l16) * DQK + quad * 8);

    const unsigned short* kbase = Kb + (32 * kh + l16) * DQK + quad * 8;
    const unsigned short* vbase = Vb + (size_t)(cs * 64 + l16) * NPIX + 32 * kh + quad * 8;

    f4v O[2][4];
    #pragma unroll
    for (int rt = 0; rt < 2; rt++)
        #pragma unroll
        for (int ct = 0; ct < 4; ct++) O[rt][ct] = (f4v){0.f, 0.f, 0.f, 0.f};
    float lsum[2] = {0.f, 0.f};

    s8v Kc0, Kc1, Kn0, Kn1;
    Kc0 = *(const s8v*)(kbase);
    Kc1 = *(const s8v*)(kbase + 16 * DQK);

    for (int kv2 = 0; kv2 < NPIX; kv2 += 128) {
        ATTN_STEP(Kc0, Kc1, Kn0, Kn1, kv2 + 64, kv2);
        ATTN_STEP(Kn0, Kn1, Kc0, Kc1, (kv2 + 128) & (NPIX - 1), kv2 + 64);
    }

    // row-sums for this key-half (reduce over quads; all lanes get value)
    #pragma unroll
    for (int rt = 0; rt < 2; rt++) {
        lsum[rt] += __shfl_xor(lsum[rt], 16);
        lsum[rt] += __shfl_xor(lsum[rt], 32);
    }

    if (kh == 1) {
        #pragma unroll
        for (int rt = 0; rt < 2; rt++)
            #pragma unroll
            for (int ct = 0; ct < 4; ct++)
                *(f4v*)&ldsO[cs][lane][(rt * 4 + ct) * 4] = O[rt][ct];
        if (cs == 0 && quad == 0) {
            #pragma unroll
            for (int rt = 0; rt < 2; rt++) ldsL[rt][l16] = lsum[rt];
        }
    }
    __syncthreads();

    if (kh == 0) {
        float g = gamma[0];
        float rinv[2];
        #pragma unroll
        for (int rt = 0; rt < 2; rt++)
            rinv[rt] = g / (lsum[rt] + ldsL[rt][l16]);
        #pragma unroll
        for (int rt = 0; rt < 2; rt++) {
            #pragma unroll
            for (int ct = 0; ct < 4; ct++) {
                f4v o2 = *(const f4v*)&ldsO[cs][lane][(rt * 4 + ct) * 4];
                #pragma unroll
                for (int r = 0; r < 4; r++) {
                    int ch = cs * 64 + ct * 16 + quad * 4 + r;
                    out[((size_t)b * CIN + ch) * NPIX + rowbase + rt * 16 + l16] =
                        (O[rt][ct][r] + o2[r]) * rinv[rt];
                }
            }
        }
    }
}

// ---------------------------------------------------------------------------
extern "C" void kernel_launch(void* const* d_in, const int* in_sizes, int n_in,
                              void* d_out, int out_size, void* d_ws, size_t ws_size,
                              hipStream_t stream) {
    const float* x     = (const float*)d_in[0];
    const float* Wq    = (const float*)d_in[1];
    const float* bq    = (const float*)d_in[2];
    const float* Wk    = (const float*)d_in[3];
    const float* bk    = (const float*)d_in[4];
    const float* Wv    = (const float*)d_in[5];
    const float* bv    = (const float*)d_in[6];
    const float* gamma = (const float*)d_in[7];
    float* out = (float*)d_out;

    char* p = (char*)d_ws;
    unsigned short* Qb = (unsigned short*)p; p += (size_t)4 * NPIX * DQK * 2;   // 1 MB
    unsigned short* Kb = (unsigned short*)p; p += (size_t)4 * NPIX * DQK * 2;   // 1 MB
    unsigned short* Vt = (unsigned short*)p; p += (size_t)4 * CIN * NPIX * 2;   // 8 MB

    prep_kernel<<<512, 256, 0, stream>>>(x, Wq, bq, Wk, bk, Wv, bv, Qb, Kb, Vt);
    attn_kernel<<<512, 512, 0, stream>>>(Qb, Kb, Vt, gamma, out);
}